// Round 1
// baseline (4366.711 us; speedup 1.0000x reference)
//
#include <hip/hip_runtime.h>
#include <hip/hip_bf16.h>
#include <cstdint>

#define HIDDEN 1024
#define INPUT  256
#define BATCH  64
#define TSTEPS 512
#define NGCOL  4096      // 4*HIDDEN
#define KTOT   1280      // HIDDEN + INPUT

typedef __attribute__((ext_vector_type(8))) short bf16x8;
typedef __attribute__((ext_vector_type(4))) float f32x4;

__device__ inline short f2bs(float f) {
    union { __hip_bfloat16 h; short s; } u;
    u.h = __float2bfloat16(f);
    return u.s;
}

// ---------------------------------------------------------------------------
// P1: build unified transposed bf16 weights Wt[4096 cols][1280 k]
//     k in [0,1024)   -> W_hh[k][col]
//     k in [1024,1280) -> W_ih[k-1024][col]
// thread t: col = t & 4095, k-chunk = t >> 12 (16 k each). Reads coalesced.
__global__ __launch_bounds__(256) void build_wt(
    const float* __restrict__ Whh, const float* __restrict__ Wih,
    __hip_bfloat16* __restrict__ Wt)
{
    int t = blockIdx.x * 256 + threadIdx.x;   // 0 .. 4096*80-1
    int col = t & 4095;
    int k0  = (t >> 12) * 16;                 // 0..1264
    __hip_bfloat16 tmp[16];
    if (k0 < HIDDEN) {
        #pragma unroll
        for (int i = 0; i < 16; ++i)
            tmp[i] = __float2bfloat16(Whh[(size_t)(k0 + i) * NGCOL + col]);
    } else {
        #pragma unroll
        for (int i = 0; i < 16; ++i)
            tmp[i] = __float2bfloat16(Wih[(size_t)(k0 - HIDDEN + i) * NGCOL + col]);
    }
    #pragma unroll
    for (int i = 0; i < 16; ++i)
        Wt[(size_t)col * KTOT + k0 + i] = tmp[i];
}

// ---------------------------------------------------------------------------
// P2: bias = b_ih + b_hh ; zero c state and h(0) buffer
__global__ __launch_bounds__(256) void init_state(
    const float* __restrict__ bih, const float* __restrict__ bhh,
    float* __restrict__ bias, float* __restrict__ cbuf,
    __hip_bfloat16* __restrict__ h0)
{
    int i = blockIdx.x * 256 + threadIdx.x;   // 65536 threads
    if (i < NGCOL) bias[i] = bih[i] + bhh[i];
    cbuf[i] = 0.f;
    h0[i] = __float2bfloat16(0.f);
}

// ---------------------------------------------------------------------------
// Step kernel: gates[64][4096] = [h(t-1) | x_t] @ Wt^T ; activations; c,h update
// 256 wgs: wg (bg,cg) owns batches bg*16..+15, h-cols cg*16..+15 (4 gate tiles)
// 8 waves: wave w handles K-chunks {w, w+8, w+16, w+24, w+32} (chunk = 32 k)
// chunks 0..31 read h (bf16), chunks 32..39 read x (fp32 -> bf16 on the fly)
__global__ __launch_bounds__(512) void lstm_step(
    const __hip_bfloat16* __restrict__ Wt,
    const float* __restrict__ x,
    const __hip_bfloat16* __restrict__ h_in,
    __hip_bfloat16* __restrict__ h_out,
    float* __restrict__ h_f32,
    float* __restrict__ cbuf,
    const float* __restrict__ bias,
    int t)
{
    __shared__ float pbuf[8][1025];   // per-wave partial gate tiles (padded)

    const int tid  = threadIdx.x;
    const int wg   = blockIdx.x;
    const int bg   = wg >> 6;         // 0..3   batch group
    const int cg   = wg & 63;         // 0..63  h-col group
    const int wave = tid >> 6;
    const int lane = tid & 63;
    const int l15  = lane & 15;
    const int l4   = lane >> 4;
    const int b0   = bg * 16;
    const int n0   = cg * 16;

    const __hip_bfloat16* hrow = h_in + (size_t)(b0 + l15) * HIDDEN;
    const float*          xrow = x + ((size_t)(b0 + l15) * TSTEPS + t) * INPUT;
    const __hip_bfloat16* wrow = Wt + (size_t)(n0 + l15) * KTOT;

    f32x4 acc0 = {0.f, 0.f, 0.f, 0.f};
    f32x4 acc1 = acc0, acc2 = acc0, acc3 = acc0;

    #pragma unroll
    for (int c5 = 0; c5 < 5; ++c5) {
        const int chunk = wave + c5 * 8;       // 0..39 (uniform per wave)
        const int kk = chunk * 32 + l4 * 8;
        bf16x8 af;
        if (chunk < 32) {
            af = *(const bf16x8*)(hrow + kk);
        } else {
            const float* xf = xrow + (kk - HIDDEN);
            float4 a = *(const float4*)(xf);
            float4 b = *(const float4*)(xf + 4);
            af[0] = f2bs(a.x); af[1] = f2bs(a.y); af[2] = f2bs(a.z); af[3] = f2bs(a.w);
            af[4] = f2bs(b.x); af[5] = f2bs(b.y); af[6] = f2bs(b.z); af[7] = f2bs(b.w);
        }
        const __hip_bfloat16* wb = wrow + kk;
        bf16x8 bf0 = *(const bf16x8*)(wb);
        bf16x8 bf1 = *(const bf16x8*)(wb + (size_t)1024 * KTOT);
        bf16x8 bf2 = *(const bf16x8*)(wb + (size_t)2048 * KTOT);
        bf16x8 bf3 = *(const bf16x8*)(wb + (size_t)3072 * KTOT);
        acc0 = __builtin_amdgcn_mfma_f32_16x16x32_bf16(af, bf0, acc0, 0, 0, 0);
        acc1 = __builtin_amdgcn_mfma_f32_16x16x32_bf16(af, bf1, acc1, 0, 0, 0);
        acc2 = __builtin_amdgcn_mfma_f32_16x16x32_bf16(af, bf2, acc2, 0, 0, 0);
        acc3 = __builtin_amdgcn_mfma_f32_16x16x32_bf16(af, bf3, acc3, 0, 0, 0);
    }

    // D layout (m89-verified): row = l4*4 + r (batch), col = l15 (h-col)
    float* pw = &pbuf[wave][0];
    #pragma unroll
    for (int r = 0; r < 4; ++r) {
        const int row = l4 * 4 + r;
        pw[(0 * 16 + row) * 16 + l15] = acc0[r];
        pw[(1 * 16 + row) * 16 + l15] = acc1[r];
        pw[(2 * 16 + row) * 16 + l15] = acc2[r];
        pw[(3 * 16 + row) * 16 + l15] = acc3[r];
    }
    __syncthreads();

    if (tid < 256) {
        const int br = tid >> 4;   // batch within group
        const int hc = tid & 15;   // h-col within group
        float gi = 0.f, gf = 0.f, gg = 0.f, go = 0.f;
        #pragma unroll
        for (int w = 0; w < 8; ++w) {
            const float* p = &pbuf[w][0];
            gi += p[(0 * 16 + br) * 16 + hc];
            gf += p[(1 * 16 + br) * 16 + hc];
            gg += p[(2 * 16 + br) * 16 + hc];
            go += p[(3 * 16 + br) * 16 + hc];
        }
        gi += bias[0 * 1024 + n0 + hc];
        gf += bias[1 * 1024 + n0 + hc];
        gg += bias[2 * 1024 + n0 + hc];
        go += bias[3 * 1024 + n0 + hc];

        const float i_ = 1.f / (1.f + __expf(-gi));
        const float f_ = 1.f / (1.f + __expf(-gf));
        const float g_ = tanhf(gg);
        const float o_ = 1.f / (1.f + __expf(-go));

        const size_t idx = (size_t)(b0 + br) * HIDDEN + n0 + hc;
        const float c = f_ * cbuf[idx] + i_ * g_;
        cbuf[idx] = c;
        const float h = o_ * tanhf(c);
        h_out[idx] = __float2bfloat16(h);
        if (t == TSTEPS - 1) h_f32[idx] = h;
    }
}

// ---------------------------------------------------------------------------
// Epilogue: out[64][256] = h_last(fp32) @ W_out + b_out
__global__ __launch_bounds__(256) void out_proj(
    const float* __restrict__ hf, const float* __restrict__ Wout,
    const float* __restrict__ bout, float* __restrict__ out)
{
    const int b  = blockIdx.x;    // 64
    const int oc = threadIdx.x;   // 256
    const float* hb = hf + (size_t)b * HIDDEN;
    float a0 = 0.f, a1 = 0.f, a2 = 0.f, a3 = 0.f;
    for (int k = 0; k < HIDDEN; k += 4) {
        a0 += hb[k + 0] * Wout[(size_t)(k + 0) * 256 + oc];
        a1 += hb[k + 1] * Wout[(size_t)(k + 1) * 256 + oc];
        a2 += hb[k + 2] * Wout[(size_t)(k + 2) * 256 + oc];
        a3 += hb[k + 3] * Wout[(size_t)(k + 3) * 256 + oc];
    }
    out[b * 256 + oc] = (a0 + a1) + (a2 + a3) + bout[oc];
}

// ---------------------------------------------------------------------------
extern "C" void kernel_launch(void* const* d_in, const int* in_sizes, int n_in,
                              void* d_out, int out_size, void* d_ws, size_t ws_size,
                              hipStream_t stream)
{
    const float* x    = (const float*)d_in[0];
    const float* Wih  = (const float*)d_in[1];
    const float* Whh  = (const float*)d_in[2];
    const float* bih  = (const float*)d_in[3];
    const float* bhh  = (const float*)d_in[4];
    const float* Wout = (const float*)d_in[5];
    const float* bout = (const float*)d_in[6];
    float* out = (float*)d_out;

    char* ws = (char*)d_ws;
    size_t off = 0;
    auto alloc = [&](size_t bytes) -> void* {
        void* p = ws + off;
        off = (off + bytes + 255) & ~(size_t)255;
        return p;
    };
    __hip_bfloat16* Wt  = (__hip_bfloat16*)alloc((size_t)NGCOL * KTOT * 2); // 10 MB
    __hip_bfloat16* hb0 = (__hip_bfloat16*)alloc((size_t)BATCH * HIDDEN * 2);
    __hip_bfloat16* hb1 = (__hip_bfloat16*)alloc((size_t)BATCH * HIDDEN * 2);
    float* cbuf = (float*)alloc((size_t)BATCH * HIDDEN * 4);
    float* bias = (float*)alloc((size_t)NGCOL * 4);
    float* hf   = (float*)alloc((size_t)BATCH * HIDDEN * 4);

    build_wt<<<1280, 256, 0, stream>>>(Whh, Wih, Wt);
    init_state<<<256, 256, 0, stream>>>(bih, bhh, bias, cbuf, hb0);

    for (int t = 0; t < TSTEPS; ++t) {
        const __hip_bfloat16* hin = (t & 1) ? hb1 : hb0;
        __hip_bfloat16* hout      = (t & 1) ? hb0 : hb1;
        lstm_step<<<256, 512, 0, stream>>>(Wt, x, hin, hout, hf, cbuf, bias, t);
    }

    out_proj<<<64, 256, 0, stream>>>(hf, Wout, bout, out);
}